// Round 4
// baseline (205.519 us; speedup 1.0000x reference)
//
#include <hip/hip_runtime.h>

// MGN_NET: 3x NNConv(mean) + ReLU, then pairwise-L1 CBT [35x35].
// All fp32. ws layout (floats):
//   x1[35*256]@0, x2[35*256]@8960, x3[35*64]@17920,
//   agg1[8960]@20160, agg2[8960]@29120, agg3[2240]@38080, cnt[35]@40320

#define NN 35
#define NE 1190
#define TE 10   // edges per edge-group; 1190 = 119*10 exactly
#define NG 119

__global__ void zero_k(float* p, int n) {
    int t = blockIdx.x * 256 + threadIdx.x;
    if (t < n) p[t] = 0.f;
}

// Layer 1: c_in=1, c_out=256. 2 edges/block x 256 o.
__global__ __launch_bounds__(512) void msg1_k(
    const float* __restrict__ x, const float* __restrict__ ea,
    const int* __restrict__ ei, const float* __restrict__ w1,
    const float* __restrict__ b1w, float* __restrict__ agg1,
    float* __restrict__ cnt) {
    int tid = threadIdx.x;
    int e = blockIdx.x * 2 + (tid >> 8);
    int o = tid & 255;
    int src = ei[e];
    int dst = ei[NE + e];
    float xs = x[src];
    const float* eap = ea + e * 6;
    const float* w = w1 + o * 6;
    float d = b1w[o];
#pragma unroll
    for (int v = 0; v < 6; v++) d = fmaf(eap[v], w[v], d);
    atomicAdd(agg1 + dst * 256 + o, xs * fmaxf(d, 0.f));
    if (o == 0) atomicAdd(cnt + dst, 1.0f);
}

__global__ __launch_bounds__(256) void x1_k(
    const float* __restrict__ x, const float* __restrict__ lin1,
    const float* __restrict__ b1, const float* __restrict__ agg1,
    const float* __restrict__ cnt, float* __restrict__ x1) {
    int n = blockIdx.x, o = threadIdx.x;
    float c = fmaxf(cnt[n], 1.f);
    float v = agg1[n * 256 + o] / c + x[n] * lin1[o] + b1[o];
    x1[n * 256 + o] = fmaxf(v, 0.f);
}

// Layer 2: c_in=256, c_out=256.
// Grid = 119 edge-groups x 4 o-groups; block 512 = 64 o-lanes x 8 i-chunks(32 i).
// Per block: w2 slice [256 i][64 o] once (0.39 MB) -> total ~218 MB from L2.
// Edge-MLP evaluated as te-pairs (two indep FMA chains) to enable v_pk_fma_f32.
__global__ __launch_bounds__(512, 4) void msg2_k(
    const float* __restrict__ x1, const float* __restrict__ ea,
    const int* __restrict__ ei, const float* __restrict__ w2,
    const float* __restrict__ b2w, float* __restrict__ agg2) {
    __shared__ __attribute__((aligned(16))) float xs[TE][256];
    __shared__ float eas[TE][6];
    __shared__ int dsts[TE];
    __shared__ int srcs[TE];
    __shared__ float part[7][TE][64];
    int tid = threadIdx.x;
    int eg = blockIdx.x >> 2;
    int og = blockIdx.x & 3;
    int e0 = eg * TE;
    if (tid < TE) { dsts[tid] = ei[NE + e0 + tid]; srcs[tid] = ei[e0 + tid]; }
    if (tid >= 64 && tid < 64 + TE * 6) {
        int t = tid - 64;
        eas[t / 6][t % 6] = ea[e0 * 6 + t];
    }
    __syncthreads();
    for (int idx = tid; idx < TE * 64; idx += 512) {
        int te = idx >> 6, q = idx & 63;
        ((float4*)xs[te])[q] = ((const float4*)(x1 + srcs[te] * 256))[q];
    }
    __syncthreads();
    int ol = tid & 63;
    int o = og * 64 + ol;
    int ic = tid >> 6;  // 0..7, i in [ic*32, ic*32+32)
    float eareg[TE][6];
#pragma unroll
    for (int te = 0; te < TE; te++)
#pragma unroll
        for (int v = 0; v < 6; v++) eareg[te][v] = eas[te][v];
    float acc[TE] = {};
    for (int ii = 0; ii < 32; ii++) {
        int i = ic * 32 + ii;
        const float* w = w2 + (size_t)(i * 256 + o) * 6;
        float2 wa = *(const float2*)w;
        float2 wb = *(const float2*)(w + 2);
        float2 wc = *(const float2*)(w + 4);
        float b = b2w[i * 256 + o];
#pragma unroll
        for (int te = 0; te < TE; te += 2) {
            float dx = b, dy = b;
            dx = fmaf(eareg[te][0], wa.x, dx); dy = fmaf(eareg[te + 1][0], wa.x, dy);
            dx = fmaf(eareg[te][1], wa.y, dx); dy = fmaf(eareg[te + 1][1], wa.y, dy);
            dx = fmaf(eareg[te][2], wb.x, dx); dy = fmaf(eareg[te + 1][2], wb.x, dy);
            dx = fmaf(eareg[te][3], wb.y, dx); dy = fmaf(eareg[te + 1][3], wb.y, dy);
            dx = fmaf(eareg[te][4], wc.x, dx); dy = fmaf(eareg[te + 1][4], wc.x, dy);
            dx = fmaf(eareg[te][5], wc.y, dx); dy = fmaf(eareg[te + 1][5], wc.y, dy);
            dx = fmaxf(dx, 0.f);               dy = fmaxf(dy, 0.f);
            acc[te] = fmaf(xs[te][i], dx, acc[te]);
            acc[te + 1] = fmaf(xs[te + 1][i], dy, acc[te + 1]);
        }
    }
    if (ic > 0) {
#pragma unroll
        for (int te = 0; te < TE; te++) part[ic - 1][te][ol] = acc[te];
    }
    __syncthreads();
    if (ic == 0) {
#pragma unroll
        for (int te = 0; te < TE; te++) {
            float s = acc[te];
#pragma unroll
            for (int p = 0; p < 7; p++) s += part[p][te][ol];
            atomicAdd(agg2 + dsts[te] * 256 + o, s);
        }
    }
}

__global__ __launch_bounds__(1024) void x2_k(
    const float* __restrict__ x1, const float* __restrict__ lin2,
    const float* __restrict__ b2, const float* __restrict__ agg2,
    const float* __restrict__ cnt, float* __restrict__ x2) {
    __shared__ float xr[256];
    __shared__ float part[3][256];
    int n = blockIdx.x, tid = threadIdx.x;
    int o = tid & 255, ic = tid >> 8;
    if (tid < 256) xr[tid] = x1[n * 256 + tid];
    __syncthreads();
    const float4* w = (const float4*)(lin2 + (size_t)o * 256 + ic * 64);
    float s = 0.f;
#pragma unroll
    for (int k = 0; k < 16; k++) {
        float4 wv = w[k];
        int i = ic * 64 + k * 4;
        s = fmaf(wv.x, xr[i], s);
        s = fmaf(wv.y, xr[i + 1], s);
        s = fmaf(wv.z, xr[i + 2], s);
        s = fmaf(wv.w, xr[i + 3], s);
    }
    if (ic > 0) part[ic - 1][o] = s;
    __syncthreads();
    if (ic == 0) {
        float tot = s + part[0][o] + part[1][o] + part[2][o];
        float c = fmaxf(cnt[n], 1.f);
        float v = agg2[n * 256 + o] / c + tot + b2[o];
        x2[n * 256 + o] = fmaxf(v, 0.f);
    }
}

// Layer 3: c_in=256, c_out=64.
// Grid = 119 edge-groups x 4 i-groups (64 i each); block 512 = 64 o x 8 ic (8 i).
__global__ __launch_bounds__(512, 4) void msg3_k(
    const float* __restrict__ x2, const float* __restrict__ ea,
    const int* __restrict__ ei, const float* __restrict__ w3,
    const float* __restrict__ b3w, float* __restrict__ agg3) {
    __shared__ __attribute__((aligned(16))) float xs[TE][64];
    __shared__ float eas[TE][6];
    __shared__ int dsts[TE];
    __shared__ int srcs[TE];
    __shared__ float part[7][TE][64];
    int tid = threadIdx.x;
    int eg = blockIdx.x >> 2;
    int ig = blockIdx.x & 3;
    int e0 = eg * TE;
    if (tid < TE) { dsts[tid] = ei[NE + e0 + tid]; srcs[tid] = ei[e0 + tid]; }
    if (tid >= 64 && tid < 64 + TE * 6) {
        int t = tid - 64;
        eas[t / 6][t % 6] = ea[e0 * 6 + t];
    }
    __syncthreads();
    for (int idx = tid; idx < TE * 16; idx += 512) {
        int te = idx >> 4, q = idx & 15;
        ((float4*)xs[te])[q] =
            ((const float4*)(x2 + srcs[te] * 256 + ig * 64))[q];
    }
    __syncthreads();
    int ol = tid & 63;
    int ic = tid >> 6;  // 0..7, 8 local i each
    float eareg[TE][6];
#pragma unroll
    for (int te = 0; te < TE; te++)
#pragma unroll
        for (int v = 0; v < 6; v++) eareg[te][v] = eas[te][v];
    float acc[TE] = {};
    for (int jj = 0; jj < 8; jj++) {
        int ii = ic * 8 + jj;            // local i (0..63)
        int i = ig * 64 + ii;            // global i
        const float* w = w3 + (size_t)(i * 64 + ol) * 6;
        float2 wa = *(const float2*)w;
        float2 wb = *(const float2*)(w + 2);
        float2 wc = *(const float2*)(w + 4);
        float b = b3w[i * 64 + ol];
#pragma unroll
        for (int te = 0; te < TE; te += 2) {
            float dx = b, dy = b;
            dx = fmaf(eareg[te][0], wa.x, dx); dy = fmaf(eareg[te + 1][0], wa.x, dy);
            dx = fmaf(eareg[te][1], wa.y, dx); dy = fmaf(eareg[te + 1][1], wa.y, dy);
            dx = fmaf(eareg[te][2], wb.x, dx); dy = fmaf(eareg[te + 1][2], wb.x, dy);
            dx = fmaf(eareg[te][3], wb.y, dx); dy = fmaf(eareg[te + 1][3], wb.y, dy);
            dx = fmaf(eareg[te][4], wc.x, dx); dy = fmaf(eareg[te + 1][4], wc.x, dy);
            dx = fmaf(eareg[te][5], wc.y, dx); dy = fmaf(eareg[te + 1][5], wc.y, dy);
            dx = fmaxf(dx, 0.f);               dy = fmaxf(dy, 0.f);
            acc[te] = fmaf(xs[te][ii], dx, acc[te]);
            acc[te + 1] = fmaf(xs[te + 1][ii], dy, acc[te + 1]);
        }
    }
    if (ic > 0) {
#pragma unroll
        for (int te = 0; te < TE; te++) part[ic - 1][te][ol] = acc[te];
    }
    __syncthreads();
    if (ic == 0) {
#pragma unroll
        for (int te = 0; te < TE; te++) {
            float s = acc[te];
#pragma unroll
            for (int p = 0; p < 7; p++) s += part[p][te][ol];
            atomicAdd(agg3 + dsts[te] * 64 + ol, s);
        }
    }
}

// Fused x3 + CBT: single block of 1024. x3 tile padded to pitch 65 to avoid
// the stride-64 LDS bank conflict in the pairwise-L1 stage.
__global__ __launch_bounds__(1024) void x3cbt_k(
    const float* __restrict__ x2, const float* __restrict__ lin3,
    const float* __restrict__ b3, const float* __restrict__ agg3,
    const float* __restrict__ cnt, float* __restrict__ out) {
    __shared__ float x2s[NN * 256];
    __shared__ float x3s[NN * 65];
    int tid = threadIdx.x;
    for (int idx = tid; idx < NN * 256; idx += 1024) x2s[idx] = x2[idx];
    __syncthreads();
    for (int j = tid; j < NN * 64; j += 1024) {
        int n = j >> 6, o = j & 63;
        const float4* w = (const float4*)(lin3 + (size_t)o * 256);
        const float* xr = x2s + n * 256;
        float s0 = 0.f, s1 = 0.f;
#pragma unroll 8
        for (int k = 0; k < 64; k += 2) {
            float4 wa = w[k], wb = w[k + 1];
            int i = k * 4;
            s0 = fmaf(wa.x, xr[i], s0);
            s0 = fmaf(wa.y, xr[i + 1], s0);
            s0 = fmaf(wa.z, xr[i + 2], s0);
            s0 = fmaf(wa.w, xr[i + 3], s0);
            s1 = fmaf(wb.x, xr[i + 4], s1);
            s1 = fmaf(wb.y, xr[i + 5], s1);
            s1 = fmaf(wb.z, xr[i + 6], s1);
            s1 = fmaf(wb.w, xr[i + 7], s1);
        }
        float c = fmaxf(cnt[n], 1.f);
        x3s[n * 65 + o] = fmaxf(agg3[j] / c + s0 + s1 + b3[o], 0.f);
    }
    __syncthreads();
    for (int p = tid; p < NN * NN; p += 1024) {
        int i = p / NN, j = p % NN;
        const float* a = x3s + i * 65;
        const float* b = x3s + j * 65;
        float s = 0.f;
#pragma unroll
        for (int f = 0; f < 64; f++) s += fabsf(a[f] - b[f]);
        out[p] = s;
    }
}

extern "C" void kernel_launch(void* const* d_in, const int* in_sizes, int n_in,
                              void* d_out, int out_size, void* d_ws, size_t ws_size,
                              hipStream_t stream) {
    const float* x    = (const float*)d_in[0];
    const float* ea   = (const float*)d_in[1];
    const int*   ei   = (const int*)d_in[2];
    const float* nn1w = (const float*)d_in[3];
    const float* nn1b = (const float*)d_in[4];
    const float* lin1 = (const float*)d_in[5];
    const float* b1   = (const float*)d_in[6];
    const float* nn2w = (const float*)d_in[7];
    const float* nn2b = (const float*)d_in[8];
    const float* lin2 = (const float*)d_in[9];
    const float* b2   = (const float*)d_in[10];
    const float* nn3w = (const float*)d_in[11];
    const float* nn3b = (const float*)d_in[12];
    const float* lin3 = (const float*)d_in[13];
    const float* b3   = (const float*)d_in[14];

    float* ws   = (float*)d_ws;
    float* x1   = ws;
    float* x2   = ws + 8960;
    float* agg1 = ws + 20160;
    float* agg2 = ws + 29120;
    float* agg3 = ws + 38080;
    float* cnt  = ws + 40320;
    float* out  = (float*)d_out;

    // zero agg1..cnt (contiguous 20195 floats starting at agg1)
    zero_k<<<(20195 + 255) / 256, 256, 0, stream>>>(agg1, 20195);
    msg1_k<<<NE / 2, 512, 0, stream>>>(x, ea, ei, nn1w, nn1b, agg1, cnt);
    x1_k<<<NN, 256, 0, stream>>>(x, lin1, b1, agg1, cnt, x1);
    msg2_k<<<NG * 4, 512, 0, stream>>>(x1, ea, ei, nn2w, nn2b, agg2);
    x2_k<<<NN, 1024, 0, stream>>>(x1, lin2, b2, agg2, cnt, x2);
    msg3_k<<<NG * 4, 512, 0, stream>>>(x2, ea, ei, nn3w, nn3b, agg3);
    x3cbt_k<<<1, 1024, 0, stream>>>(x2, lin3, b3, agg3, cnt, out);
}

// Round 5
// 146.462 us; speedup vs baseline: 1.4032x; 1.4032x over previous
//
#include <hip/hip_runtime.h>

// MGN_NET: 3x NNConv(mean) + ReLU, then pairwise-L1 CBT [35x35].
// All fp32. ws layout (floats):
//   x1[35*256]@0, x2[35*256]@8960, x3[35*64]@17920,
//   agg1[8960]@20160, agg2[8960]@29120, agg3[2240]@38080, cnt[35]@40320

#define NN 35
#define NE 1190
#define TE 10   // edges per edge-group; 1190 = 119*10 exactly
#define NG 119

__global__ void zero_k(float* p, int n) {
    int t = blockIdx.x * 256 + threadIdx.x;
    if (t < n) p[t] = 0.f;
}

// Layer 1: c_in=1, c_out=256. 2 edges/block x 256 o.
__global__ __launch_bounds__(512) void msg1_k(
    const float* __restrict__ x, const float* __restrict__ ea,
    const int* __restrict__ ei, const float* __restrict__ w1,
    const float* __restrict__ b1w, float* __restrict__ agg1,
    float* __restrict__ cnt) {
    int tid = threadIdx.x;
    int e = blockIdx.x * 2 + (tid >> 8);
    int o = tid & 255;
    int src = ei[e];
    int dst = ei[NE + e];
    float xs = x[src];
    const float* eap = ea + e * 6;
    const float* w = w1 + o * 6;
    float d = b1w[o];
#pragma unroll
    for (int v = 0; v < 6; v++) d = fmaf(eap[v], w[v], d);
    atomicAdd(agg1 + dst * 256 + o, xs * fmaxf(d, 0.f));
    if (o == 0) atomicAdd(cnt + dst, 1.0f);
}

__global__ __launch_bounds__(256) void x1_k(
    const float* __restrict__ x, const float* __restrict__ lin1,
    const float* __restrict__ b1, const float* __restrict__ agg1,
    const float* __restrict__ cnt, float* __restrict__ x1) {
    int n = blockIdx.x, o = threadIdx.x;
    float c = fmaxf(cnt[n], 1.f);
    float v = agg1[n * 256 + o] / c + x[n] * lin1[o] + b1[o];
    x1[n * 256 + o] = fmaxf(v, 0.f);
}

// Layer 2: c_in=256, c_out=256.
// Grid = 119 edge-groups x 4 o-groups; block 512 = 64 o-lanes x 8 i-chunks(32 i).
// Per block: w2 slice [256 i][64 o] once (0.39 MB) -> total ~218 MB from L2.
// Edge-MLP evaluated as te-pairs (two indep FMA chains) to enable v_pk_fma_f32.
__global__ __launch_bounds__(512, 4) void msg2_k(
    const float* __restrict__ x1, const float* __restrict__ ea,
    const int* __restrict__ ei, const float* __restrict__ w2,
    const float* __restrict__ b2w, float* __restrict__ agg2) {
    __shared__ __attribute__((aligned(16))) float xs[TE][256];
    __shared__ float eas[TE][6];
    __shared__ int dsts[TE];
    __shared__ int srcs[TE];
    __shared__ float part[7][TE][64];
    int tid = threadIdx.x;
    int eg = blockIdx.x >> 2;
    int og = blockIdx.x & 3;
    int e0 = eg * TE;
    if (tid < TE) { dsts[tid] = ei[NE + e0 + tid]; srcs[tid] = ei[e0 + tid]; }
    if (tid >= 64 && tid < 64 + TE * 6) {
        int t = tid - 64;
        eas[t / 6][t % 6] = ea[e0 * 6 + t];
    }
    __syncthreads();
    for (int idx = tid; idx < TE * 64; idx += 512) {
        int te = idx >> 6, q = idx & 63;
        ((float4*)xs[te])[q] = ((const float4*)(x1 + srcs[te] * 256))[q];
    }
    __syncthreads();
    int ol = tid & 63;
    int o = og * 64 + ol;
    int ic = tid >> 6;  // 0..7, i in [ic*32, ic*32+32)
    float eareg[TE][6];
#pragma unroll
    for (int te = 0; te < TE; te++)
#pragma unroll
        for (int v = 0; v < 6; v++) eareg[te][v] = eas[te][v];
    float acc[TE] = {};
    for (int ii = 0; ii < 32; ii++) {
        int i = ic * 32 + ii;
        const float* w = w2 + (size_t)(i * 256 + o) * 6;
        float2 wa = *(const float2*)w;
        float2 wb = *(const float2*)(w + 2);
        float2 wc = *(const float2*)(w + 4);
        float b = b2w[i * 256 + o];
#pragma unroll
        for (int te = 0; te < TE; te += 2) {
            float dx = b, dy = b;
            dx = fmaf(eareg[te][0], wa.x, dx); dy = fmaf(eareg[te + 1][0], wa.x, dy);
            dx = fmaf(eareg[te][1], wa.y, dx); dy = fmaf(eareg[te + 1][1], wa.y, dy);
            dx = fmaf(eareg[te][2], wb.x, dx); dy = fmaf(eareg[te + 1][2], wb.x, dy);
            dx = fmaf(eareg[te][3], wb.y, dx); dy = fmaf(eareg[te + 1][3], wb.y, dy);
            dx = fmaf(eareg[te][4], wc.x, dx); dy = fmaf(eareg[te + 1][4], wc.x, dy);
            dx = fmaf(eareg[te][5], wc.y, dx); dy = fmaf(eareg[te + 1][5], wc.y, dy);
            dx = fmaxf(dx, 0.f);               dy = fmaxf(dy, 0.f);
            acc[te] = fmaf(xs[te][i], dx, acc[te]);
            acc[te + 1] = fmaf(xs[te + 1][i], dy, acc[te + 1]);
        }
    }
    if (ic > 0) {
#pragma unroll
        for (int te = 0; te < TE; te++) part[ic - 1][te][ol] = acc[te];
    }
    __syncthreads();
    if (ic == 0) {
#pragma unroll
        for (int te = 0; te < TE; te++) {
            float s = acc[te];
#pragma unroll
            for (int p = 0; p < 7; p++) s += part[p][te][ol];
            atomicAdd(agg2 + dsts[te] * 256 + o, s);
        }
    }
}

__global__ __launch_bounds__(1024) void x2_k(
    const float* __restrict__ x1, const float* __restrict__ lin2,
    const float* __restrict__ b2, const float* __restrict__ agg2,
    const float* __restrict__ cnt, float* __restrict__ x2) {
    __shared__ float xr[256];
    __shared__ float part[3][256];
    int n = blockIdx.x, tid = threadIdx.x;
    int o = tid & 255, ic = tid >> 8;
    if (tid < 256) xr[tid] = x1[n * 256 + tid];
    __syncthreads();
    const float4* w = (const float4*)(lin2 + (size_t)o * 256 + ic * 64);
    float s = 0.f;
#pragma unroll
    for (int k = 0; k < 16; k++) {
        float4 wv = w[k];
        int i = ic * 64 + k * 4;
        s = fmaf(wv.x, xr[i], s);
        s = fmaf(wv.y, xr[i + 1], s);
        s = fmaf(wv.z, xr[i + 2], s);
        s = fmaf(wv.w, xr[i + 3], s);
    }
    if (ic > 0) part[ic - 1][o] = s;
    __syncthreads();
    if (ic == 0) {
        float tot = s + part[0][o] + part[1][o] + part[2][o];
        float c = fmaxf(cnt[n], 1.f);
        float v = agg2[n * 256 + o] / c + tot + b2[o];
        x2[n * 256 + o] = fmaxf(v, 0.f);
    }
}

// Layer 3: c_in=256, c_out=64.
// Grid = 119 edge-groups x 4 i-groups (64 i each); block 512 = 64 o x 8 ic (8 i).
__global__ __launch_bounds__(512, 4) void msg3_k(
    const float* __restrict__ x2, const float* __restrict__ ea,
    const int* __restrict__ ei, const float* __restrict__ w3,
    const float* __restrict__ b3w, float* __restrict__ agg3) {
    __shared__ __attribute__((aligned(16))) float xs[TE][64];
    __shared__ float eas[TE][6];
    __shared__ int dsts[TE];
    __shared__ int srcs[TE];
    __shared__ float part[7][TE][64];
    int tid = threadIdx.x;
    int eg = blockIdx.x >> 2;
    int ig = blockIdx.x & 3;
    int e0 = eg * TE;
    if (tid < TE) { dsts[tid] = ei[NE + e0 + tid]; srcs[tid] = ei[e0 + tid]; }
    if (tid >= 64 && tid < 64 + TE * 6) {
        int t = tid - 64;
        eas[t / 6][t % 6] = ea[e0 * 6 + t];
    }
    __syncthreads();
    for (int idx = tid; idx < TE * 16; idx += 512) {
        int te = idx >> 4, q = idx & 15;
        ((float4*)xs[te])[q] =
            ((const float4*)(x2 + srcs[te] * 256 + ig * 64))[q];
    }
    __syncthreads();
    int ol = tid & 63;
    int ic = tid >> 6;  // 0..7, 8 local i each
    float eareg[TE][6];
#pragma unroll
    for (int te = 0; te < TE; te++)
#pragma unroll
        for (int v = 0; v < 6; v++) eareg[te][v] = eas[te][v];
    float acc[TE] = {};
    for (int jj = 0; jj < 8; jj++) {
        int ii = ic * 8 + jj;            // local i (0..63)
        int i = ig * 64 + ii;            // global i
        const float* w = w3 + (size_t)(i * 64 + ol) * 6;
        float2 wa = *(const float2*)w;
        float2 wb = *(const float2*)(w + 2);
        float2 wc = *(const float2*)(w + 4);
        float b = b3w[i * 64 + ol];
#pragma unroll
        for (int te = 0; te < TE; te += 2) {
            float dx = b, dy = b;
            dx = fmaf(eareg[te][0], wa.x, dx); dy = fmaf(eareg[te + 1][0], wa.x, dy);
            dx = fmaf(eareg[te][1], wa.y, dx); dy = fmaf(eareg[te + 1][1], wa.y, dy);
            dx = fmaf(eareg[te][2], wb.x, dx); dy = fmaf(eareg[te + 1][2], wb.x, dy);
            dx = fmaf(eareg[te][3], wb.y, dx); dy = fmaf(eareg[te + 1][3], wb.y, dy);
            dx = fmaf(eareg[te][4], wc.x, dx); dy = fmaf(eareg[te + 1][4], wc.x, dy);
            dx = fmaf(eareg[te][5], wc.y, dx); dy = fmaf(eareg[te + 1][5], wc.y, dy);
            dx = fmaxf(dx, 0.f);               dy = fmaxf(dy, 0.f);
            acc[te] = fmaf(xs[te][ii], dx, acc[te]);
            acc[te + 1] = fmaf(xs[te + 1][ii], dy, acc[te + 1]);
        }
    }
    if (ic > 0) {
#pragma unroll
        for (int te = 0; te < TE; te++) part[ic - 1][te][ol] = acc[te];
    }
    __syncthreads();
    if (ic == 0) {
#pragma unroll
        for (int te = 0; te < TE; te++) {
            float s = acc[te];
#pragma unroll
            for (int p = 0; p < 7; p++) s += part[p][te][ol];
            atomicAdd(agg3 + dsts[te] * 64 + ol, s);
        }
    }
}

// x3: 35 blocks x 256 thr (4 i-chunks x 64 o) — spreads the per-lane lin3 row
// gather across 35 CUs' L1s (single-block fusion was a 69us L1-serialization
// disaster; never again).
__global__ __launch_bounds__(256) void x3_k(
    const float* __restrict__ x2, const float* __restrict__ lin3,
    const float* __restrict__ b3, const float* __restrict__ agg3,
    const float* __restrict__ cnt, float* __restrict__ x3) {
    __shared__ float xr[256];
    __shared__ float part[3][64];
    int n = blockIdx.x, tid = threadIdx.x;
    int o = tid & 63, ic = tid >> 6;  // 4 chunks of 64
    xr[tid] = x2[n * 256 + tid];
    __syncthreads();
    const float4* w = (const float4*)(lin3 + (size_t)o * 256 + ic * 64);
    float s = 0.f;
#pragma unroll
    for (int k = 0; k < 16; k++) {
        float4 wv = w[k];
        int i = ic * 64 + k * 4;
        s = fmaf(wv.x, xr[i], s);
        s = fmaf(wv.y, xr[i + 1], s);
        s = fmaf(wv.z, xr[i + 2], s);
        s = fmaf(wv.w, xr[i + 3], s);
    }
    if (ic > 0) part[ic - 1][o] = s;
    __syncthreads();
    if (ic == 0) {
        float tot = s + part[0][o] + part[1][o] + part[2][o];
        float c = fmaxf(cnt[n], 1.f);
        x3[n * 64 + o] = fmaxf(agg3[n * 64 + o] / c + tot + b3[o], 0.f);
    }
}

__global__ __launch_bounds__(256) void cbt_k(const float* __restrict__ x3,
                                             float* __restrict__ out) {
    int t = blockIdx.x * 256 + threadIdx.x;
    if (t >= NN * NN) return;
    int i = t / NN, j = t % NN;
    const float* a = x3 + i * 64;
    const float* b = x3 + j * 64;
    float s = 0.f;
#pragma unroll
    for (int f = 0; f < 64; f++) s += fabsf(a[f] - b[f]);
    out[t] = s;
}

extern "C" void kernel_launch(void* const* d_in, const int* in_sizes, int n_in,
                              void* d_out, int out_size, void* d_ws, size_t ws_size,
                              hipStream_t stream) {
    const float* x    = (const float*)d_in[0];
    const float* ea   = (const float*)d_in[1];
    const int*   ei   = (const int*)d_in[2];
    const float* nn1w = (const float*)d_in[3];
    const float* nn1b = (const float*)d_in[4];
    const float* lin1 = (const float*)d_in[5];
    const float* b1   = (const float*)d_in[6];
    const float* nn2w = (const float*)d_in[7];
    const float* nn2b = (const float*)d_in[8];
    const float* lin2 = (const float*)d_in[9];
    const float* b2   = (const float*)d_in[10];
    const float* nn3w = (const float*)d_in[11];
    const float* nn3b = (const float*)d_in[12];
    const float* lin3 = (const float*)d_in[13];
    const float* b3   = (const float*)d_in[14];

    float* ws   = (float*)d_ws;
    float* x1   = ws;
    float* x2   = ws + 8960;
    float* x3v  = ws + 17920;
    float* agg1 = ws + 20160;
    float* agg2 = ws + 29120;
    float* agg3 = ws + 38080;
    float* cnt  = ws + 40320;
    float* out  = (float*)d_out;

    // zero agg1..cnt (contiguous 20195 floats starting at agg1)
    zero_k<<<(20195 + 255) / 256, 256, 0, stream>>>(agg1, 20195);
    msg1_k<<<NE / 2, 512, 0, stream>>>(x, ea, ei, nn1w, nn1b, agg1, cnt);
    x1_k<<<NN, 256, 0, stream>>>(x, lin1, b1, agg1, cnt, x1);
    msg2_k<<<NG * 4, 512, 0, stream>>>(x1, ea, ei, nn2w, nn2b, agg2);
    x2_k<<<NN, 1024, 0, stream>>>(x1, lin2, b2, agg2, cnt, x2);
    msg3_k<<<NG * 4, 512, 0, stream>>>(x2, ea, ei, nn3w, nn3b, agg3);
    x3_k<<<NN, 256, 0, stream>>>(x2, lin3, b3, agg3, cnt, x3v);
    cbt_k<<<(NN * NN + 255) / 256, 256, 0, stream>>>(x3v, out);
}

// Round 6
// 139.988 us; speedup vs baseline: 1.4681x; 1.0462x over previous
//
#include <hip/hip_runtime.h>

// MGN_NET: 3x NNConv(mean) + ReLU, then pairwise-L1 CBT [35x35]. All fp32.
// 6 dispatches: prep(zero+lin2T) -> msg1 -> msg2(+x1 recompute) ->
//               msg3(+x2 slice recompute, +35 x2-writer blocks) -> x3 -> cbt
// ws layout (floats): agg1@0[8960], agg2@8960[8960], agg3@17920[2240],
//   cnt@20160[35] (zero span 20195), lin2T@20224[65536], x2m@85760[8960],
//   x3@94720[2240]

#define NN 35
#define NE 1190
#define TE 10   // edges per edge-group; 1190 = 119*10 exactly
#define NG 119

#define OFF_AGG1 0
#define OFF_AGG2 8960
#define OFF_AGG3 17920
#define OFF_CNT  20160
#define ZERO_N   20195
#define OFF_L2T  20224
#define OFF_X2M  85760
#define OFF_X3   94720

// prep: blocks 0..79 zero agg1/agg2/agg3/cnt; blocks 80..335 repack
// lin2T[i][o] = lin2[o][i] (coalesced writes; 64-line gather reads are tiny).
__global__ __launch_bounds__(256) void prep_k(float* __restrict__ ws,
                                              const float* __restrict__ lin2) {
    int b = blockIdx.x, t = threadIdx.x;
    if (b < 80) {
        int idx = b * 256 + t;
        if (idx < ZERO_N) ws[idx] = 0.f;
    } else {
        int i = b - 80;
        ws[OFF_L2T + i * 256 + t] = lin2[t * 256 + i];
    }
}

// Layer 1: c_in=1, c_out=256. 2 edges/block x 256 o.
__global__ __launch_bounds__(512) void msg1_k(
    const float* __restrict__ x, const float* __restrict__ ea,
    const int* __restrict__ ei, const float* __restrict__ w1,
    const float* __restrict__ b1w, float* __restrict__ agg1,
    float* __restrict__ cnt) {
    int tid = threadIdx.x;
    int e = blockIdx.x * 2 + (tid >> 8);
    int o = tid & 255;
    int src = ei[e];
    int dst = ei[NE + e];
    float xs = x[src];
    const float* eap = ea + e * 6;
    const float* w = w1 + o * 6;
    float d = b1w[o];
#pragma unroll
    for (int v = 0; v < 6; v++) d = fmaf(eap[v], w[v], d);
    atomicAdd(agg1 + dst * 256 + o, xs * fmaxf(d, 0.f));
    if (o == 0) atomicAdd(cnt + dst, 1.0f);
}

// Layer 2 (+x1 recompute): grid 119 eg x 4 og; block 512 = 64 ol x 8 ic.
__global__ __launch_bounds__(512, 4) void msg2x1_k(
    const float* __restrict__ x, const float* __restrict__ ea,
    const int* __restrict__ ei, const float* __restrict__ lin1,
    const float* __restrict__ b1, const float* __restrict__ agg1,
    const float* __restrict__ cnt, const float* __restrict__ w2,
    const float* __restrict__ b2w, float* __restrict__ agg2) {
    __shared__ float xs[TE][256];
    __shared__ float eas[TE][6];
    __shared__ int srcs[TE], dsts[TE];
    __shared__ float part[7][TE][64];
    int tid = threadIdx.x;
    int eg = blockIdx.x >> 2, og = blockIdx.x & 3;
    int e0 = eg * TE;
    if (tid < TE) { srcs[tid] = ei[e0 + tid]; dsts[tid] = ei[NE + e0 + tid]; }
    if (tid >= 64 && tid < 64 + TE * 6) {
        int t = tid - 64;
        eas[t / 6][t % 6] = ea[e0 * 6 + t];
    }
    __syncthreads();
    // x1 recompute: xs[te][i] = relu(agg1[s,i]/c + x[s]*lin1[i] + b1[i])
    for (int idx = tid; idx < TE * 256; idx += 512) {
        int te = idx >> 8, i = idx & 255;
        int s = srcs[te];
        float c = fmaxf(cnt[s], 1.f);
        float v = agg1[s * 256 + i] / c + x[s] * lin1[i] + b1[i];
        xs[te][i] = fmaxf(v, 0.f);
    }
    __syncthreads();
    int ol = tid & 63;
    int o = og * 64 + ol;
    int ic = tid >> 6;  // 8 chunks of 32 i
    float eareg[TE][6];
#pragma unroll
    for (int te = 0; te < TE; te++)
#pragma unroll
        for (int v = 0; v < 6; v++) eareg[te][v] = eas[te][v];
    float acc[TE] = {};
    for (int ii = 0; ii < 32; ii++) {
        int i = ic * 32 + ii;
        const float* w = w2 + (size_t)(i * 256 + o) * 6;
        float2 wa = *(const float2*)w;
        float2 wb = *(const float2*)(w + 2);
        float2 wc = *(const float2*)(w + 4);
        float b = b2w[i * 256 + o];
#pragma unroll
        for (int te = 0; te < TE; te += 2) {
            float dx = b, dy = b;
            dx = fmaf(eareg[te][0], wa.x, dx); dy = fmaf(eareg[te + 1][0], wa.x, dy);
            dx = fmaf(eareg[te][1], wa.y, dx); dy = fmaf(eareg[te + 1][1], wa.y, dy);
            dx = fmaf(eareg[te][2], wb.x, dx); dy = fmaf(eareg[te + 1][2], wb.x, dy);
            dx = fmaf(eareg[te][3], wb.y, dx); dy = fmaf(eareg[te + 1][3], wb.y, dy);
            dx = fmaf(eareg[te][4], wc.x, dx); dy = fmaf(eareg[te + 1][4], wc.x, dy);
            dx = fmaf(eareg[te][5], wc.y, dx); dy = fmaf(eareg[te + 1][5], wc.y, dy);
            dx = fmaxf(dx, 0.f);               dy = fmaxf(dy, 0.f);
            acc[te] = fmaf(xs[te][i], dx, acc[te]);
            acc[te + 1] = fmaf(xs[te + 1][i], dy, acc[te + 1]);
        }
    }
    if (ic > 0) {
#pragma unroll
        for (int te = 0; te < TE; te++) part[ic - 1][te][ol] = acc[te];
    }
    __syncthreads();
    if (ic == 0) {
#pragma unroll
        for (int te = 0; te < TE; te++) {
            float s = acc[te];
#pragma unroll
            for (int p = 0; p < 7; p++) s += part[p][te][ol];
            atomicAdd(agg2 + dsts[te] * 256 + o, s);
        }
    }
}

// Layer 3 (+x2 slice recompute via lin2T): blocks 0..475 = msg work
// (eg = b>>2, ig = b&3, x2 channels [ig*64, ig*64+64)); blocks 476..510
// materialize full x2 row (n = b-476) into x2m for x3_k.
__global__ __launch_bounds__(512, 4) void msg3x2_k(
    const float* __restrict__ x, const float* __restrict__ ea,
    const int* __restrict__ ei, const float* __restrict__ lin1,
    const float* __restrict__ b1, const float* __restrict__ agg1,
    const float* __restrict__ cnt, const float* __restrict__ lin2T,
    const float* __restrict__ b2, const float* __restrict__ agg2,
    const float* __restrict__ w3, const float* __restrict__ b3w,
    float* __restrict__ agg3, float* __restrict__ x2m) {
    __shared__ float x1r[TE][256];
    __shared__ float xs[TE][64];
    __shared__ float eas[TE][6];
    __shared__ int srcs[TE], dsts[TE];
    __shared__ float part[7][TE][64];
    int tid = threadIdx.x;

    if (blockIdx.x >= 476) {
        // x2 writer for node n: x2m[n,o] = relu(agg2/c + lin2.x1 + b2)
        int n = blockIdx.x - 476;
        float c = fmaxf(cnt[n], 1.f);
        if (tid < 256) {
            float v = agg1[n * 256 + tid] / c + x[n] * lin1[tid] + b1[tid];
            x1r[0][tid] = fmaxf(v, 0.f);
        }
        __syncthreads();
        int o = tid & 255, ic = tid >> 8;  // 2 chunks of 128 i
        float s = 0.f;
        for (int ii = 0; ii < 128; ii++) {
            int i = ic * 128 + ii;
            s = fmaf(lin2T[i * 256 + o], x1r[0][i], s);
        }
        float* p2 = &part[0][0][0];
        if (ic == 1) p2[o] = s;
        __syncthreads();
        if (ic == 0) {
            float v = agg2[n * 256 + o] / c + s + p2[o] + b2[o];
            x2m[n * 256 + o] = fmaxf(v, 0.f);
        }
        return;
    }

    int eg = blockIdx.x >> 2, ig = blockIdx.x & 3;
    int e0 = eg * TE;
    if (tid < TE) { srcs[tid] = ei[e0 + tid]; dsts[tid] = ei[NE + e0 + tid]; }
    if (tid >= 64 && tid < 64 + TE * 6) {
        int t = tid - 64;
        eas[t / 6][t % 6] = ea[e0 * 6 + t];
    }
    __syncthreads();
    // x1 rows
    for (int idx = tid; idx < TE * 256; idx += 512) {
        int te = idx >> 8, i = idx & 255;
        int s = srcs[te];
        float c = fmaxf(cnt[s], 1.f);
        float v = agg1[s * 256 + i] / c + x[s] * lin1[i] + b1[i];
        x1r[te][i] = fmaxf(v, 0.f);
    }
    __syncthreads();
    int ol = tid & 63;
    int ic = tid >> 6;             // 8 chunks
    int o2 = ig * 64 + ol;         // x2 channel this block needs
    // x2 slice: xs[te][ol] = relu(agg2[s,o2]/c + sum_i lin2T[i][o2]*x1r[te][i] + b2[o2])
    {
        float acc2[TE] = {};
        for (int ii = 0; ii < 32; ii++) {
            int i = ic * 32 + ii;
            float w = lin2T[i * 256 + o2];
#pragma unroll
            for (int te = 0; te < TE; te++)
                acc2[te] = fmaf(w, x1r[te][i], acc2[te]);
        }
        if (ic > 0) {
#pragma unroll
            for (int te = 0; te < TE; te++) part[ic - 1][te][ol] = acc2[te];
        }
        __syncthreads();
        if (ic == 0) {
#pragma unroll
            for (int te = 0; te < TE; te++) {
                float ssum = acc2[te];
#pragma unroll
                for (int p = 0; p < 7; p++) ssum += part[p][te][ol];
                int s = srcs[te];
                float c = fmaxf(cnt[s], 1.f);
                float v = agg2[s * 256 + o2] / c + ssum + b2[o2];
                xs[te][ol] = fmaxf(v, 0.f);
            }
        }
        __syncthreads();
    }
    // main msg3 loop: i global = ig*64 + ii, ii = ic*8 + jj
    float eareg[TE][6];
#pragma unroll
    for (int te = 0; te < TE; te++)
#pragma unroll
        for (int v = 0; v < 6; v++) eareg[te][v] = eas[te][v];
    float acc[TE] = {};
    for (int jj = 0; jj < 8; jj++) {
        int ii = ic * 8 + jj;
        int i = ig * 64 + ii;
        const float* w = w3 + (size_t)(i * 64 + ol) * 6;
        float2 wa = *(const float2*)w;
        float2 wb = *(const float2*)(w + 2);
        float2 wc = *(const float2*)(w + 4);
        float b = b3w[i * 64 + ol];
#pragma unroll
        for (int te = 0; te < TE; te += 2) {
            float dx = b, dy = b;
            dx = fmaf(eareg[te][0], wa.x, dx); dy = fmaf(eareg[te + 1][0], wa.x, dy);
            dx = fmaf(eareg[te][1], wa.y, dx); dy = fmaf(eareg[te + 1][1], wa.y, dy);
            dx = fmaf(eareg[te][2], wb.x, dx); dy = fmaf(eareg[te + 1][2], wb.x, dy);
            dx = fmaf(eareg[te][3], wb.y, dx); dy = fmaf(eareg[te + 1][3], wb.y, dy);
            dx = fmaf(eareg[te][4], wc.x, dx); dy = fmaf(eareg[te + 1][4], wc.x, dy);
            dx = fmaf(eareg[te][5], wc.y, dx); dy = fmaf(eareg[te + 1][5], wc.y, dy);
            dx = fmaxf(dx, 0.f);               dy = fmaxf(dy, 0.f);
            acc[te] = fmaf(xs[te][ii], dx, acc[te]);
            acc[te + 1] = fmaf(xs[te + 1][ii], dy, acc[te + 1]);
        }
    }
    if (ic > 0) {
#pragma unroll
        for (int te = 0; te < TE; te++) part[ic - 1][te][ol] = acc[te];
    }
    __syncthreads();
    if (ic == 0) {
#pragma unroll
        for (int te = 0; te < TE; te++) {
            float s = acc[te];
#pragma unroll
            for (int p = 0; p < 7; p++) s += part[p][te][ol];
            atomicAdd(agg3 + dsts[te] * 64 + ol, s);
        }
    }
}

// x3: 35 blocks x 256 thr (64 o x 4 i-chunks); per-lane lin3 row gather is
// fine at this block count (L1s of 35 CUs). Reads materialized x2m.
__global__ __launch_bounds__(256) void x3_k(
    const float* __restrict__ x2m, const float* __restrict__ lin3,
    const float* __restrict__ b3, const float* __restrict__ agg3,
    const float* __restrict__ cnt, float* __restrict__ x3) {
    __shared__ float xr[256];
    __shared__ float part[3][64];
    int n = blockIdx.x, tid = threadIdx.x;
    int o = tid & 63, ic = tid >> 6;
    xr[tid] = x2m[n * 256 + tid];
    __syncthreads();
    const float4* w = (const float4*)(lin3 + (size_t)o * 256 + ic * 64);
    float s = 0.f;
#pragma unroll
    for (int k = 0; k < 16; k++) {
        float4 wv = w[k];
        int i = ic * 64 + k * 4;
        s = fmaf(wv.x, xr[i], s);
        s = fmaf(wv.y, xr[i + 1], s);
        s = fmaf(wv.z, xr[i + 2], s);
        s = fmaf(wv.w, xr[i + 3], s);
    }
    if (ic > 0) part[ic - 1][o] = s;
    __syncthreads();
    if (ic == 0) {
        float tot = s + part[0][o] + part[1][o] + part[2][o];
        float c = fmaxf(cnt[n], 1.f);
        x3[n * 64 + o] = fmaxf(agg3[n * 64 + o] / c + tot + b3[o], 0.f);
    }
}

__global__ __launch_bounds__(256) void cbt_k(const float* __restrict__ x3,
                                             float* __restrict__ out) {
    int t = blockIdx.x * 256 + threadIdx.x;
    if (t >= NN * NN) return;
    int i = t / NN, j = t % NN;
    const float* a = x3 + i * 64;
    const float* b = x3 + j * 64;
    float s = 0.f;
#pragma unroll
    for (int f = 0; f < 64; f++) s += fabsf(a[f] - b[f]);
    out[t] = s;
}

extern "C" void kernel_launch(void* const* d_in, const int* in_sizes, int n_in,
                              void* d_out, int out_size, void* d_ws, size_t ws_size,
                              hipStream_t stream) {
    const float* x    = (const float*)d_in[0];
    const float* ea   = (const float*)d_in[1];
    const int*   ei   = (const int*)d_in[2];
    const float* nn1w = (const float*)d_in[3];
    const float* nn1b = (const float*)d_in[4];
    const float* lin1 = (const float*)d_in[5];
    const float* b1   = (const float*)d_in[6];
    const float* nn2w = (const float*)d_in[7];
    const float* nn2b = (const float*)d_in[8];
    const float* lin2 = (const float*)d_in[9];
    const float* b2   = (const float*)d_in[10];
    const float* nn3w = (const float*)d_in[11];
    const float* nn3b = (const float*)d_in[12];
    const float* lin3 = (const float*)d_in[13];
    const float* b3   = (const float*)d_in[14];

    float* ws    = (float*)d_ws;
    float* agg1  = ws + OFF_AGG1;
    float* agg2  = ws + OFF_AGG2;
    float* agg3  = ws + OFF_AGG3;
    float* cnt   = ws + OFF_CNT;
    float* lin2T = ws + OFF_L2T;
    float* x2m   = ws + OFF_X2M;
    float* x3v   = ws + OFF_X3;
    float* out   = (float*)d_out;

    prep_k<<<336, 256, 0, stream>>>(ws, lin2);
    msg1_k<<<NE / 2, 512, 0, stream>>>(x, ea, ei, nn1w, nn1b, agg1, cnt);
    msg2x1_k<<<NG * 4, 512, 0, stream>>>(x, ea, ei, lin1, b1, agg1, cnt,
                                         nn2w, nn2b, agg2);
    msg3x2_k<<<NG * 4 + NN, 512, 0, stream>>>(x, ea, ei, lin1, b1, agg1, cnt,
                                              lin2T, b2, agg2, nn3w, nn3b,
                                              agg3, x2m);
    x3_k<<<NN, 256, 0, stream>>>(x2m, lin3, b3, agg3, cnt, x3v);
    cbt_k<<<(NN * NN + 255) / 256, 256, 0, stream>>>(x3v, out);
}